// Round 5
// baseline (126.666 us; speedup 1.0000x reference)
//
#include <hip/hip_runtime.h>
#include <stdint.h>

#define B_ 64
#define T_ 4096
#define H_ 256
#define U_ 256

typedef float f32x4 __attribute__((ext_vector_type(4)));
typedef short short8 __attribute__((ext_vector_type(8)));
typedef short short4v __attribute__((ext_vector_type(4)));

__device__ __forceinline__ short bf16rne(float f) {
    uint32_t x = __builtin_bit_cast(uint32_t, f);
    return (short)((x + 0x7FFFu + ((x >> 16) & 1u)) >> 16);
}

__device__ __forceinline__ float fast_tanh(float x) {
    float e = __expf(2.0f * x);
    return 1.0f - 2.0f * __builtin_amdgcn_rcpf(e + 1.0f);
}

// ---- fused prep: blocks 0-255 convert W2 -> w2t[u][h] bf16; blocks 256-319 qproj ----
__global__ __launch_bounds__(256) void k_prep(const float* __restrict__ W2,
                                              uint16_t* __restrict__ w2t,
                                              const float* __restrict__ query,
                                              const float* __restrict__ W1,
                                              const float* __restrict__ b1,
                                              const float* __restrict__ b2,
                                              float* __restrict__ qpc) {
    if (blockIdx.x < 256) {
        int idx = blockIdx.x * 256 + threadIdx.x;
        int h = idx >> 8;
        int u = idx & 255;
        w2t[u * 256 + h] = (uint16_t)bf16rne(W2[idx]);
    } else {
        __shared__ float qrow[H_];
        int b = blockIdx.x - 256, u = threadIdx.x;
        qrow[u] = query[b * H_ + u];
        __syncthreads();
        float acc = b1[u] + b2[u];
#pragma unroll 8
        for (int h = 0; h < H_; ++h) acc += qrow[h] * W1[h * U_ + u];
        qpc[b * U_ + u] = acc;
    }
}

// ---------------- fused main (one barrier per tile, coalesced loads) ----------------
// 512 thr = 8 waves.  Wave w owns u in [w*32, w*32+32) (A = W2 frags in regs).
// Load: instr j of wave w covers tile row j*8+w contiguously (lane l -> bytes l*16).
// Consume: lanes 0-3 of wave w compute exp(score) for rows {w,w+8,w+16,w+24}, shfl-
// broadcast; every thread accumulates ctx partial for cols l*4..l*4+3 in fp32.
// Unnormalized exp safe: |score| <= sum|V_u| (<= ~16 typ) -> fp32 never overflows.
#define TR 32
#define NT 8
__global__ __launch_bounds__(512, 2) void k_main(const float* __restrict__ values,
                                                 const uint16_t* __restrict__ w2t,
                                                 const float* __restrict__ qpc,
                                                 const float* __restrict__ V,
                                                 float* __restrict__ score,
                                                 float* __restrict__ part_O,
                                                 float* __restrict__ part_s) {
    __shared__ __align__(16) char Ab[2][TR * 512];   // bf16 [32][256] x2, byte^=((row&7)<<4)
    __shared__ float red[2][TR][12];                 // [parity][row][wave], 48B rows (16B-aligned)
    __shared__ float Ored[8][256];                   // per-wave ctx partials
    __shared__ float sred[8];

    const int tid = threadIdx.x;
    const int wg = blockIdx.x;          // 0..1023
    const int b = wg >> 4;
    const int chunk = (wg & 15) * (NT * TR);

    const int w = tid >> 6;             // wave 0..7
    const int l = tid & 63;
    const int c = l & 15;
    const int g = l >> 4;

    // A fragments (W2) in regs: 2 strips x 8 ks (64 VGPR)
    short8 afr[2][8];
#pragma unroll
    for (int s = 0; s < 2; ++s) {
        const uint16_t* ap = w2t + (size_t)(w * 32 + s * 16 + c) * 256 + g * 8;
#pragma unroll
        for (int ks = 0; ks < 8; ++ks) afr[s][ks] = *(const short8*)(ap + ks * 32);
    }
    float qv[2][4], vv[2][4];
#pragma unroll
    for (int s = 0; s < 2; ++s)
#pragma unroll
        for (int r = 0; r < 4; ++r) {
            int u = w * 32 + s * 16 + g * 4 + r;
            qv[s][r] = qpc[b * U_ + u];
            vv[s][r] = V[u];
        }

    const float* vbase = values + (size_t)b * T_ * H_ + (size_t)chunk * H_;
    // per-thread load offsets: instr j -> tile row j*8+w, lane bytes l*16
    // stage dst: row j*8+w, col l*4 (bf16), swizzle (w&7)<<4 == w<<4
    const int sswz = (l * 8) ^ (w << 4);

    f32x4 vt[3][4];                     // rotating fp32 tiles, prefetch distance 2
    float Oacc[4] = {0.f, 0.f, 0.f, 0.f};
    float sacc = 0.f;

    // prologue: load tiles 0,1
#pragma unroll
    for (int j = 0; j < 4; ++j) {
        vt[0][j] = *(const f32x4*)(vbase + j * 2048 + w * 256 + l * 4);
        vt[1][j] = *(const f32x4*)(vbase + 8192 + j * 2048 + w * 256 + l * 4);
    }
    // stage tile 0 -> Ab[0]
#pragma unroll
    for (int j = 0; j < 4; ++j) {
        short4v s4;
        s4[0] = bf16rne(vt[0][j][0]); s4[1] = bf16rne(vt[0][j][1]);
        s4[2] = bf16rne(vt[0][j][2]); s4[3] = bf16rne(vt[0][j][3]);
        *(short4v*)(Ab[0] + (j * 8 + w) * 512 + sswz) = s4;
    }

#pragma unroll
    for (int t = 0; t < NT; ++t) {
        __syncthreads();    // Ab[t&1] staged; red[(t-1)&1] complete
        // ---- consume tile t-1: weights + fp32 ctx accumulation ----
        if (t > 0) {
            const int os = (t + 2) % 3;     // slot of tile t-1
            float p = 0.f;
            if (l < 4) {
                const float* rr = &red[(t - 1) & 1][l * 8 + w][0];
                f32x4 r0 = *(const f32x4*)(rr);
                f32x4 r1 = *(const f32x4*)(rr + 4);
                float ssum = (r0[0] + r0[1] + r0[2] + r0[3]) +
                             (r1[0] + r1[1] + r1[2] + r1[3]);
                p = __expf(ssum);
                sacc += p;
                score[(size_t)b * T_ + chunk + (t - 1) * TR + l * 8 + w] = ssum;
            }
#pragma unroll
            for (int j = 0; j < 4; ++j) {
                float wgt = __shfl(p, j, 64);
                Oacc[0] += wgt * vt[os][j][0];
                Oacc[1] += wgt * vt[os][j][1];
                Oacc[2] += wgt * vt[os][j][2];
                Oacc[3] += wgt * vt[os][j][3];
            }
        }
        // ---- prefetch tile t+2 into freed slot ----
        if (t + 2 < NT) {
            const int ns = (t + 2) % 3;
            const float* nb = vbase + (size_t)(t + 2) * 8192;
#pragma unroll
            for (int j = 0; j < 4; ++j)
                vt[ns][j] = *(const f32x4*)(nb + j * 2048 + w * 256 + l * 4);
        }
        // ---- stage tile t+1 -> Ab[(t+1)&1] ----
        if (t + 1 < NT) {
            const int cs = (t + 1) % 3;
#pragma unroll
            for (int j = 0; j < 4; ++j) {
                short4v s4;
                s4[0] = bf16rne(vt[cs][j][0]); s4[1] = bf16rne(vt[cs][j][1]);
                s4[2] = bf16rne(vt[cs][j][2]); s4[3] = bf16rne(vt[cs][j][3]);
                *(short4v*)(Ab[(t + 1) & 1] + (j * 8 + w) * 512 + sswz) = s4;
            }
        }
        // ---- MFMA on tile t ----
#pragma unroll
        for (int sub = 0; sub < 2; ++sub) {
            const char* rp = Ab[t & 1] + (sub * 16 + c) * 512;
            const int swz = (c & 7) << 4;
            f32x4 acc0 = (f32x4)(0.0f);
            f32x4 acc1 = (f32x4)(0.0f);
#pragma unroll
            for (int ks = 0; ks < 8; ++ks) {
                short8 bf = *(const short8*)(rp + ((ks * 64 + g * 16) ^ swz));
                acc0 = __builtin_amdgcn_mfma_f32_16x16x32_bf16(afr[0][ks], bf, acc0, 0, 0, 0);
                acc1 = __builtin_amdgcn_mfma_f32_16x16x32_bf16(afr[1][ks], bf, acc1, 0, 0, 0);
            }
            float p = 0.f;
#pragma unroll
            for (int r = 0; r < 4; ++r) {
                p += fast_tanh(acc0[r] + qv[0][r]) * vv[0][r];
                p += fast_tanh(acc1[r] + qv[1][r]) * vv[1][r];
            }
            p += __shfl_xor(p, 16, 64);
            p += __shfl_xor(p, 32, 64);
            if (g == 0) red[t & 1][sub * 16 + c][w] = p;
        }
    }
    __syncthreads();
    {   // final consume: tile NT-1 (slot (NT-1)%3, red[(NT-1)&1])
        const int fs = (NT - 1) % 3;
        float p = 0.f;
        if (l < 4) {
            const float* rr = &red[(NT - 1) & 1][l * 8 + w][0];
            f32x4 r0 = *(const f32x4*)(rr);
            f32x4 r1 = *(const f32x4*)(rr + 4);
            float ssum = (r0[0] + r0[1] + r0[2] + r0[3]) +
                         (r1[0] + r1[1] + r1[2] + r1[3]);
            p = __expf(ssum);
            sacc += p;
            score[(size_t)b * T_ + chunk + (NT - 1) * TR + l * 8 + w] = ssum;
        }
#pragma unroll
        for (int j = 0; j < 4; ++j) {
            float wgt = __shfl(p, j, 64);
            Oacc[0] += wgt * vt[fs][j][0];
            Oacc[1] += wgt * vt[fs][j][1];
            Oacc[2] += wgt * vt[fs][j][2];
            Oacc[3] += wgt * vt[fs][j][3];
        }
    }
    // write per-wave partials
    *(f32x4*)(&Ored[w][l * 4]) = *(f32x4*)Oacc;
    sacc += __shfl_xor(sacc, 1, 64);
    sacc += __shfl_xor(sacc, 2, 64);
    if (l == 0) sred[w] = sacc;
    __syncthreads();
    if (tid < 256) {
        float o = 0.f;
#pragma unroll
        for (int j = 0; j < 8; ++j) o += Ored[j][tid];
        part_O[(size_t)wg * 256 + tid] = o;
    }
    if (tid == 0) {
        float sb = 0.f;
#pragma unroll
        for (int j = 0; j < 8; ++j) sb += sred[j];
        part_s[wg] = sb;
    }
}

// ---------------- finish: reduce partials, write ctx + normalized weights ----------------
__global__ __launch_bounds__(256) void k_fin(const float* __restrict__ part_O,
                                             const float* __restrict__ part_s,
                                             const float* __restrict__ score,
                                             float* __restrict__ ctx,
                                             float* __restrict__ weights) {
    int b = blockIdx.x >> 3;
    int j = blockIdx.x & 7;
    int col = threadIdx.x;
    float sb = 0.f;
#pragma unroll
    for (int ch = 0; ch < 16; ++ch) sb += part_s[b * 16 + ch];
    float inv = 1.0f / sb;
    if (j == 0) {
        float o = 0.f;
#pragma unroll
        for (int ch = 0; ch < 16; ++ch) o += part_O[(size_t)(b * 16 + ch) * 256 + col];
        ctx[b * H_ + col] = o * inv;
    }
#pragma unroll
    for (int i = 0; i < 2; ++i) {
        int idx = j * 512 + i * 256 + col;
        float s = score[(size_t)b * T_ + idx];
        weights[(size_t)b * T_ + idx] = __expf(s) * inv;
    }
}

extern "C" void kernel_launch(void* const* d_in, const int* in_sizes, int n_in,
                              void* d_out, int out_size, void* d_ws, size_t ws_size,
                              hipStream_t stream) {
    const float* query  = (const float*)d_in[0];
    const float* values = (const float*)d_in[1];
    const float* W1     = (const float*)d_in[2];
    const float* b1     = (const float*)d_in[3];
    const float* W2     = (const float*)d_in[4];
    const float* b2     = (const float*)d_in[5];
    const float* V      = (const float*)d_in[6];
    // d_in[7] = bV: softmax is shift-invariant -> no effect on outputs.

    float* out = (float*)d_out;
    float* ctx = out;                    // [B,H]
    float* weights = out + B_ * H_;      // [B,T,1]

    char* ws = (char*)d_ws;
    uint16_t* w2t   = (uint16_t*)ws;                               // 128 KB
    float* qpc      = (float*)(ws + 131072);                       // 64 KB
    float* scorebuf = (float*)(ws + 131072 + 65536);               // 1 MB
    float* part_O   = (float*)(ws + 131072 + 65536 + 1048576);     // 1 MB
    float* part_s   = (float*)(ws + 131072 + 65536 + 2097152);     // 4 KB

    k_prep<<<dim3(320), dim3(256), 0, stream>>>(W2, w2t, query, W1, b1, b2, qpc);
    k_main<<<dim3(1024), dim3(512), 0, stream>>>(values, w2t, qpc, V, scorebuf,
                                                 part_O, part_s);
    k_fin<<<dim3(512), dim3(256), 0, stream>>>(part_O, part_s, scorebuf, ctx, weights);
}

// Round 6
// 94.538 us; speedup vs baseline: 1.3398x; 1.3398x over previous
//
#include <hip/hip_runtime.h>
#include <stdint.h>

#define B_ 64
#define T_ 4096
#define H_ 256
#define U_ 256

typedef float f32x4 __attribute__((ext_vector_type(4)));
typedef short short8 __attribute__((ext_vector_type(8)));

__device__ __forceinline__ short bf16rne(float f) {
    uint32_t x = __builtin_bit_cast(uint32_t, f);
    return (short)((x + 0x7FFFu + ((x >> 16) & 1u)) >> 16);
}

__device__ __forceinline__ float fast_tanh(float x) {
    float e = __expf(2.0f * x);
    return 1.0f - 2.0f * __builtin_amdgcn_rcpf(e + 1.0f);
}

// Workgroup barrier that orders LDS only: drains lgkmcnt but lets global loads
// (vmcnt) stay in flight across the barrier. __syncthreads() would emit
// s_waitcnt vmcnt(0) and drain the HBM pipeline every tile.
__device__ __forceinline__ void wg_barrier_lds() {
    asm volatile("s_waitcnt lgkmcnt(0)" ::: "memory");
    __builtin_amdgcn_sched_barrier(0);
    __builtin_amdgcn_s_barrier();
    __builtin_amdgcn_sched_barrier(0);
}

// ---- fused prep: blocks 0-255 convert W2 -> w2t[u][h] bf16; blocks 256-319 qproj ----
__global__ __launch_bounds__(256) void k_prep(const float* __restrict__ W2,
                                              uint16_t* __restrict__ w2t,
                                              const float* __restrict__ query,
                                              const float* __restrict__ W1,
                                              const float* __restrict__ b1,
                                              const float* __restrict__ b2,
                                              float* __restrict__ qpc) {
    if (blockIdx.x < 256) {
        int idx = blockIdx.x * 256 + threadIdx.x;
        int h = idx >> 8;
        int u = idx & 255;
        w2t[u * 256 + h] = (uint16_t)bf16rne(W2[idx]);
    } else {
        __shared__ float qrow[H_];
        int b = blockIdx.x - 256, u = threadIdx.x;
        qrow[u] = query[b * H_ + u];
        __syncthreads();
        float acc = b1[u] + b2[u];
#pragma unroll 8
        for (int h = 0; h < H_; ++h) acc += qrow[h] * W1[h * U_ + u];
        qpc[b * U_ + u] = acc;
    }
}

// ---------------- fused main ----------------
// Per WG (512 thr, 8 waves, 256 t-rows): scores via swapped MFMA D[u,t] (W2 frags in
// regs, values tile bf16 XOR-swizzled in LDS), then unnormalized-softmax context
// accumulation from the fp32 prefetch registers (values read ONCE from HBM).
// Unnormalized exp is safe: |score| <= sum|V_u| ~ 13 -> exp <= 4e5, fp32-safe.
#define TR 32          // t-rows per tile
#define NT 8           // tiles per WG  -> 256 rows per WG
__global__ __launch_bounds__(512, 2) void k_main(const float* __restrict__ values,
                                                 const uint16_t* __restrict__ w2t,
                                                 const float* __restrict__ qpc,
                                                 const float* __restrict__ V,
                                                 float* __restrict__ score,
                                                 float* __restrict__ part_O,
                                                 float* __restrict__ part_s) {
    __shared__ __align__(16) char Ab[TR * 512];   // bf16 [32][256], byte ^= ((row&7)<<4)
    __shared__ float red[TR][9];                  // per-row partials from 8 waves
    __shared__ float Ored[TR][16][16];            // per-thread context partials (32 KB)
    __shared__ float sred[TR];

    const int tid = threadIdx.x;
    const int wg = blockIdx.x;          // 0..1023
    const int b = wg >> 4;
    const int chunk = (wg & 15) * (NT * TR);

    const int w = tid >> 6;             // wave 0..7
    const int l = tid & 63;
    const int c = l & 15;
    const int g = l >> 4;

    // A fragments (W2) in regs for whole kernel: 2 strips x 8 ks  (64 VGPR)
    short8 afr[2][8];
#pragma unroll
    for (int s = 0; s < 2; ++s) {
        const uint16_t* ap = w2t + (size_t)(w * 32 + s * 16 + c) * 256 + g * 8;
#pragma unroll
        for (int ks = 0; ks < 8; ++ks) afr[s][ks] = *(const short8*)(ap + ks * 32);
    }
    float qv[2][4], vv[2][4];
#pragma unroll
    for (int s = 0; s < 2; ++s)
#pragma unroll
        for (int r = 0; r < 4; ++r) {
            int u = w * 32 + s * 16 + g * 4 + r;
            qv[s][r] = qpc[b * U_ + u];
            vv[s][r] = V[u];
        }

    const float* vbase = values + (size_t)b * T_ * H_;
    const int srow = tid >> 4;          // 0..31: row this thread stages/consumes
    const int q = tid & 15;             // 16B chunk within row
    const int sswz = (srow & 7) << 4;
    char* wr0 = Ab + srow * 512 + ((q * 16) ^ sswz);
    char* wr1 = Ab + srow * 512 + ((q * 16 + 256) ^ sswz);
    const float* sbase = vbase + (size_t)srow * H_ + q * 8;

    // rotating fp32 value tiles, prefetch distance 2 (period-3 static slots)
    f32x4 vt[3][4];
    float Oacc[16];
#pragma unroll
    for (int j = 0; j < 16; ++j) Oacc[j] = 0.f;
    float sacc = 0.f;

    {   // prologue: tiles 0 and 1
        const float* nb0 = sbase + (size_t)chunk * H_;
        vt[0][0] = *(const f32x4*)(nb0);       vt[0][1] = *(const f32x4*)(nb0 + 4);
        vt[0][2] = *(const f32x4*)(nb0 + 128); vt[0][3] = *(const f32x4*)(nb0 + 132);
        const float* nb1 = sbase + (size_t)(chunk + TR) * H_;
        vt[1][0] = *(const f32x4*)(nb1);       vt[1][1] = *(const f32x4*)(nb1 + 4);
        vt[1][2] = *(const f32x4*)(nb1 + 128); vt[1][3] = *(const f32x4*)(nb1 + 132);
    }

#pragma unroll
    for (int t = 0; t < NT; ++t) {
        const int cs = t % 3;            // current tile slot (stage now)
        const int os = (t + 2) % 3;      // == (t-1)%3: old slot (consume), then load t+2
        wg_barrier_lds();                // red(t-1) ready; Ab free  (vmcnt floats)
        {   // stage tile t: fp32 regs -> bf16 swizzled LDS
            short8 s0, s1;
            s0[0] = bf16rne(vt[cs][0][0]); s0[1] = bf16rne(vt[cs][0][1]);
            s0[2] = bf16rne(vt[cs][0][2]); s0[3] = bf16rne(vt[cs][0][3]);
            s0[4] = bf16rne(vt[cs][1][0]); s0[5] = bf16rne(vt[cs][1][1]);
            s0[6] = bf16rne(vt[cs][1][2]); s0[7] = bf16rne(vt[cs][1][3]);
            s1[0] = bf16rne(vt[cs][2][0]); s1[1] = bf16rne(vt[cs][2][1]);
            s1[2] = bf16rne(vt[cs][2][2]); s1[3] = bf16rne(vt[cs][2][3]);
            s1[4] = bf16rne(vt[cs][3][0]); s1[5] = bf16rne(vt[cs][3][1]);
            s1[6] = bf16rne(vt[cs][3][2]); s1[7] = bf16rne(vt[cs][3][3]);
            *(short8*)wr0 = s0;
            *(short8*)wr1 = s1;
        }
        // consume tile t-1: scores -> weights -> context accumulation (fp32 regs)
        if (t > 0) {
            float ssum = 0.f;
#pragma unroll
            for (int j = 0; j < 8; ++j) ssum += red[srow][j];
            float wgt = __expf(ssum);
            if (q == 0) {
                sacc += wgt;
                score[(size_t)b * T_ + chunk + (t - 1) * TR + srow] = ssum;
            }
#pragma unroll
            for (int vj = 0; vj < 4; ++vj)
#pragma unroll
                for (int j = 0; j < 4; ++j)
                    Oacc[vj * 4 + j] += wgt * vt[os][vj][j];
        }
        // prefetch tile t+2 into the just-freed old slot
        if (t + 2 < NT) {
            const float* nb = sbase + (size_t)(chunk + (t + 2) * TR) * H_;
            vt[os][0] = *(const f32x4*)(nb);       vt[os][1] = *(const f32x4*)(nb + 4);
            vt[os][2] = *(const f32x4*)(nb + 128); vt[os][3] = *(const f32x4*)(nb + 132);
        }
        wg_barrier_lds();                // Ab(t) staged  (vmcnt floats)
        // MFMA phase
#pragma unroll
        for (int sub = 0; sub < 2; ++sub) {
            const char* rp = Ab + (sub * 16 + c) * 512;
            const int swz = (c & 7) << 4;
            f32x4 acc0 = (f32x4)(0.0f);
            f32x4 acc1 = (f32x4)(0.0f);
#pragma unroll
            for (int ks = 0; ks < 8; ++ks) {
                short8 bf = *(const short8*)(rp + ((ks * 64 + g * 16) ^ swz));
                acc0 = __builtin_amdgcn_mfma_f32_16x16x32_bf16(afr[0][ks], bf, acc0, 0, 0, 0);
                acc1 = __builtin_amdgcn_mfma_f32_16x16x32_bf16(afr[1][ks], bf, acc1, 0, 0, 0);
            }
            float p = 0.f;
#pragma unroll
            for (int r = 0; r < 4; ++r) {
                p += fast_tanh(acc0[r] + qv[0][r]) * vv[0][r];
                p += fast_tanh(acc1[r] + qv[1][r]) * vv[1][r];
            }
            p += __shfl_xor(p, 16, 64);
            p += __shfl_xor(p, 32, 64);
            if (g == 0) red[sub * 16 + c][w] = p;
        }
    }
    __syncthreads();
    {   // final consume: tile NT-1 (fp32 still in slot (NT-1)%3)
        const int fs = (NT - 1) % 3;
        float ssum = 0.f;
#pragma unroll
        for (int j = 0; j < 8; ++j) ssum += red[srow][j];
        float wgt = __expf(ssum);
        if (q == 0) {
            sacc += wgt;
            score[(size_t)b * T_ + chunk + (NT - 1) * TR + srow] = ssum;
        }
#pragma unroll
        for (int vj = 0; vj < 4; ++vj)
#pragma unroll
            for (int j = 0; j < 4; ++j)
                Oacc[vj * 4 + j] += wgt * vt[fs][vj][j];
    }
    // reduce per-thread context partials across the 32 rows
#pragma unroll
    for (int j = 0; j < 16; ++j) Ored[srow][q][j] = Oacc[j];
    if (q == 0) sred[srow] = sacc;
    __syncthreads();
    if (tid < 256) {
        int col = tid;
        int qq, jj;
        if (col < 128) { qq = col >> 3; jj = col & 7; }
        else           { qq = (col - 128) >> 3; jj = 8 + (col & 7); }
        float o = 0.f;
#pragma unroll
        for (int s = 0; s < TR; ++s) o += Ored[s][qq][jj];
        part_O[(size_t)wg * 256 + col] = o;
    }
    if (tid == 0) {
        float sb = 0.f;
#pragma unroll
        for (int s = 0; s < TR; ++s) sb += sred[s];
        part_s[wg] = sb;
    }
}

// ---------------- finish: reduce partials, write ctx + normalized weights ----------------
__global__ __launch_bounds__(256) void k_fin(const float* __restrict__ part_O,
                                             const float* __restrict__ part_s,
                                             const float* __restrict__ score,
                                             float* __restrict__ ctx,
                                             float* __restrict__ weights) {
    int b = blockIdx.x >> 3;
    int j = blockIdx.x & 7;
    int col = threadIdx.x;
    float sb = 0.f;
#pragma unroll
    for (int ch = 0; ch < 16; ++ch) sb += part_s[b * 16 + ch];
    float inv = 1.0f / sb;
    if (j == 0) {
        float o = 0.f;
#pragma unroll
        for (int ch = 0; ch < 16; ++ch) o += part_O[(size_t)(b * 16 + ch) * 256 + col];
        ctx[b * H_ + col] = o * inv;
    }
#pragma unroll
    for (int i = 0; i < 2; ++i) {
        int idx = j * 512 + i * 256 + col;
        float s = score[(size_t)b * T_ + idx];
        weights[(size_t)b * T_ + idx] = __expf(s) * inv;
    }
}

extern "C" void kernel_launch(void* const* d_in, const int* in_sizes, int n_in,
                              void* d_out, int out_size, void* d_ws, size_t ws_size,
                              hipStream_t stream) {
    const float* query  = (const float*)d_in[0];
    const float* values = (const float*)d_in[1];
    const float* W1     = (const float*)d_in[2];
    const float* b1     = (const float*)d_in[3];
    const float* W2     = (const float*)d_in[4];
    const float* b2     = (const float*)d_in[5];
    const float* V      = (const float*)d_in[6];
    // d_in[7] = bV: softmax is shift-invariant -> no effect on outputs.

    float* out = (float*)d_out;
    float* ctx = out;                    // [B,H]
    float* weights = out + B_ * H_;      // [B,T,1]

    char* ws = (char*)d_ws;
    uint16_t* w2t   = (uint16_t*)ws;                               // 128 KB
    float* qpc      = (float*)(ws + 131072);                       // 64 KB
    float* scorebuf = (float*)(ws + 131072 + 65536);               // 1 MB
    float* part_O   = (float*)(ws + 131072 + 65536 + 1048576);     // 1 MB
    float* part_s   = (float*)(ws + 131072 + 65536 + 2097152);     // 4 KB

    k_prep<<<dim3(320), dim3(256), 0, stream>>>(W2, w2t, query, W1, b1, b2, qpc);
    k_main<<<dim3(1024), dim3(512), 0, stream>>>(values, w2t, qpc, V, scorebuf,
                                                 part_O, part_s);
    k_fin<<<dim3(512), dim3(256), 0, stream>>>(part_O, part_s, scorebuf, ctx, weights);
}